// Round 4
// baseline (19847.011 us; speedup 1.0000x reference)
//
#include <hip/hip_runtime.h>
#include <hip/hip_bf16.h>

#define BB 32
#define SS 64
#define TT 63
#define EMBD 512
#define ENCD 1024
#define HIDD 1024
#define VV 32000
#define INTERD 2160
#define LIND 2560
#define TV (TT*VV)
#define OUT_ATT ((long)BB*TT*VV)

typedef float f32;
typedef unsigned short ushort_t;
typedef __attribute__((ext_vector_type(8))) short bf16x8;
typedef __attribute__((ext_vector_type(4))) float f32x4;
typedef __attribute__((ext_vector_type(8))) unsigned short u16x8;

// ---- ws layout (bytes) ----
#define OFF_LIN   0L
#define OFF_WD    20643840L
#define OFF_WHH0  (OFF_WD + 2097152L)
#define OFF_WIH0E (OFF_WHH0 + 8388608L)
#define OFF_WIH0C (OFF_WIH0E + 4194304L)
#define OFF_WIH1  (OFF_WIH0C + 8388608L)
#define OFF_WHH1  (OFF_WIH1 + 8388608L)
#define OFF_WEND  (OFF_WHH1 + 8388608L)      /* 60,489,728 */
#define OFF_LINBF OFF_WD                      /* post-loop alias over weights */
#define OFF_HIDBF (OFF_WD + 10485760L)
#define OFF_ENCP  OFF_WEND                    /* enc_proj f32, pre-loop only (8 MB) */
#define OFF_G0H   OFF_WEND                    /* [4][32][4096] f32  2 MB */
#define OFF_G1H   (OFF_G0H + 2097152L)        /* [4][32][4096]      2 MB */
#define OFF_G0C   (OFF_G1H + 2097152L)        /* [4][32][4096]      2 MB */
#define OFF_G1X   (OFF_G0C + 2097152L)        /* [4][32][4096]      2 MB */
#define OFF_HWD   (OFF_G1X + 2097152L)        /* [4][32][1024]      0.5 MB */
#define OFF_EPB   (OFF_HWD + 524288L)         /* enc_proj bf16 4 MB */
#define OFF_EOB   (OFF_EPB + 4194304L)        /* enc_out  bf16 4 MB */
#define OFF_EMBF  (OFF_EOB + 4194304L)        /* emb frags 2,064,384 */
#define OFF_C0    (OFF_EMBF + 2064384L)
#define OFF_C1    (OFF_C0 + 131072L)
#define OFF_H0F   (OFF_C1 + 131072L)
#define OFF_H1F   (OFF_H0F + 65536L)
#define OFF_CTXF  (OFF_H1F + 65536L)
#define OFF_CNT   (OFF_CTXF + 65536L)         /* 64 lines x 64 B */
/* total ~76.6 MB (< 91.4 MB known-safe from round 2) */

__device__ __forceinline__ f32 fast_tanh(f32 x){
    f32 e = __expf(2.0f*x);
    return 1.0f - 2.0f/(e+1.0f);
}
__device__ __forceinline__ f32 fast_sig(f32 x){
    return 1.0f/(1.0f+__expf(-x));
}
__device__ __forceinline__ ushort_t f2bf(f32 x){
    __hip_bfloat16 h = __float2bfloat16(x);
    return *(ushort_t*)&h;
}
__device__ __forceinline__ f32 bf2f(ushort_t u){
    unsigned v = ((unsigned)u) << 16;
    return __uint_as_float(v);
}

// ================= small setup kernels =================
__global__ void k_setup(const f32* __restrict__ c0in, f32* __restrict__ cst,
                        unsigned* __restrict__ cnt){
  int g = blockIdx.x*256 + threadIdx.x;
  if(g < 2*BB*HIDD) cst[g] = c0in[g];     // c0 then c1 contiguous
  if(g < 1024) cnt[g] = 0;
}

__global__ void k_fill_emb(const f32* __restrict__ emb_table, const int* __restrict__ y,
                           f32* __restrict__ lin){
  int i = blockIdx.x*256 + threadIdx.x;
  if(i >= TT*BB*EMBD) return;
  int e = i & (EMBD-1);
  int tb = i >> 9; int b = tb & 31; int t = tb >> 5;
  int tok = y[b*64 + t];
  lin[(long)(t*BB+b)*LIND + 2048 + e] = emb_table[(long)tok*EMBD + e];
}

__global__ void k_cast(const f32* __restrict__ ep, const f32* __restrict__ eo,
                       ushort_t* __restrict__ epb, ushort_t* __restrict__ eob){
  int i = blockIdx.x*256 + threadIdx.x;
  if(i >= BB*SS*ENCD) return;
  epb[i] = f2bf(ep[i]);
  eob[i] = f2bf(eo[i]);
}

// ---- fp32 tiled GEMM (enc_proj = enc_output @ We, NN) -- validated round 1-3
__global__ __launch_bounds__(256)
void k_gemm_nn(const f32* __restrict__ A, const f32* __restrict__ Bm,
               f32* __restrict__ C, int M, int N, int K, int lda, int ldb, int ldc){
  __shared__ f32 As[16][72];
  __shared__ f32 Bs[16][72];
  int tid = threadIdx.x;
  int row0 = blockIdx.x*64, col0 = blockIdx.y*64;
  int tx = tid & 15, ty = tid >> 4;
  f32 acc[4][4];
  #pragma unroll
  for(int i=0;i<4;i++)
    #pragma unroll
    for(int j=0;j<4;j++) acc[i][j]=0.f;
  int ra = tid>>2, ka = (tid&3)*4;
  int kb_ = tid>>4, nb = (tid&15)*4;
  for(int k0=0;k0<K;k0+=16){
    {
      float4 a4 = make_float4(0.f,0.f,0.f,0.f);
      int gm = row0 + ra;
      if(gm < M) a4 = *(const float4*)(A + (long)gm*lda + k0 + ka);
      As[ka+0][ra]=a4.x; As[ka+1][ra]=a4.y; As[ka+2][ra]=a4.z; As[ka+3][ra]=a4.w;
    }
    {
      float4 b4 = *(const float4*)(Bm + (long)(k0+kb_)*ldb + col0 + nb);
      *(float4*)&Bs[kb_][nb] = b4;
    }
    __syncthreads();
    #pragma unroll
    for(int kk=0;kk<16;kk++){
      float4 av = *(const float4*)&As[kk][ty*4];
      float4 bv = *(const float4*)&Bs[kk][tx*4];
      const f32* af=(const f32*)&av; const f32* bf=(const f32*)&bv;
      #pragma unroll
      for(int i=0;i<4;i++)
        #pragma unroll
        for(int j=0;j<4;j++) acc[i][j] = __builtin_fmaf(af[i], bf[j], acc[i][j]);
    }
    __syncthreads();
  }
  #pragma unroll
  for(int i=0;i<4;i++){
    int gm = row0 + ty*4 + i;
    if(gm >= M) continue;
    #pragma unroll
    for(int j=0;j<4;j++){
      int gn = col0 + tx*4 + j;
      if(gn >= N) continue;
      C[(long)gm*ldc + gn] = acc[i][j];
    }
  }
}

// ---- fp32 -> bf16 fragment tiles. tile (rsub*nkt + kt): elem (r=rsub*16+(lane&15),
// k=kt*32+(lane>>4)*8+j). tr=false: src[r*ld+k]; tr=true: src[k*ld+r]. OOB->0.
__global__ void k_conv(const f32* __restrict__ src, ushort_t* __restrict__ dst,
                       int ld, int rows, int kmax, int nkt, long ntiles, int tr){
  long g = (long)blockIdx.x*256 + threadIdx.x;
  long tile = g >> 6;
  if(tile >= ntiles) return;
  int lane = (int)(g & 63);
  int kt = (int)(tile % nkt);
  int rsub = (int)(tile / nkt);
  int r = rsub*16 + (lane&15);
  int k0 = kt*32 + ((lane>>4)<<3);
  u16x8 v;
  if(!tr && r < rows && (k0+8) <= kmax){
    float4 a = *(const float4*)(src + (long)r*ld + k0);
    float4 b = *(const float4*)(src + (long)r*ld + k0 + 4);
    v[0]=f2bf(a.x); v[1]=f2bf(a.y); v[2]=f2bf(a.z); v[3]=f2bf(a.w);
    v[4]=f2bf(b.x); v[5]=f2bf(b.y); v[6]=f2bf(b.z); v[7]=f2bf(b.w);
  } else {
    #pragma unroll
    for(int j=0;j<8;j++){
      int k = k0+j;
      f32 x = 0.f;
      if(r < rows && k < kmax) x = tr ? src[(long)k*ld + r] : src[(long)r*ld + k];
      v[j] = f2bf(x);
    }
  }
  *(u16x8*)(dst + (tile<<9) + lane*8) = v;
}

// ================= persistent loop kernel =================
// B streamed from global frag tiles
__device__ __forceinline__ void gemm_part(const ushort_t* __restrict__ Af, int ankt,
    const ushort_t* __restrict__ Bf, int bnkt, int ns, int kt0, int ktn,
    int lane, f32x4& acc0, f32x4& acc1){
  for(int kt=kt0; kt<kt0+ktn; ++kt){
    bf16x8 b  = *(const bf16x8*)(Bf + (((long)ns*bnkt + kt)<<9) + lane*8);
    bf16x8 a0 = *(const bf16x8*)(Af + (((long)kt)<<9) + lane*8);
    bf16x8 a1 = *(const bf16x8*)(Af + (((long)(ankt + kt))<<9) + lane*8);
    acc0 = __builtin_amdgcn_mfma_f32_16x16x32_bf16(a0, b, acc0, 0, 0, 0);
    acc1 = __builtin_amdgcn_mfma_f32_16x16x32_bf16(a1, b, acc1, 0, 0, 0);
  }
}
// B from LDS (8 consecutive kti tiles starting at wl), A frag-tiles from global
__device__ __forceinline__ void gemm_lds8(const ushort_t* __restrict__ wl,
    const ushort_t* __restrict__ Af, int ankt, int kt0,
    int lane, f32x4& acc0, f32x4& acc1){
  #pragma unroll
  for(int i=0;i<8;i++){
    bf16x8 b  = *(const bf16x8*)(wl + i*512 + lane*8);
    bf16x8 a0 = *(const bf16x8*)(Af + (((long)(kt0+i))<<9) + lane*8);
    bf16x8 a1 = *(const bf16x8*)(Af + (((long)(ankt + kt0 + i))<<9) + lane*8);
    acc0 = __builtin_amdgcn_mfma_f32_16x16x32_bf16(a0, b, acc0, 0, 0, 0);
    acc1 = __builtin_amdgcn_mfma_f32_16x16x32_bf16(a1, b, acc1, 0, 0, 0);
  }
}
__device__ __forceinline__ void store_part(f32* __restrict__ dst, int ns, int lane,
                                           int nstride, const f32x4& acc0, const f32x4& acc1){
  int col = ns*16 + (lane&15);
  int r0 = (lane>>4)*4;
  #pragma unroll
  for(int r=0;r<4;r++){
    dst[(long)(r0+r)*nstride + col]    = acc0[r];
    dst[(long)(16+r0+r)*nstride + col] = acc1[r];
  }
}
// A-fragment element index for (row b<32, k), nkt K-tiles
__device__ __forceinline__ long frag_idx(int b, int k, int nkt){
  return (((long)((b>>4)*nkt + (k>>5)))<<9) + ((b&15) + (((k&31)>>3)<<4))*8 + (k&7);
}

// grid barrier: 64 counter lines, wave-parallel poll (round-3-proven fence semantics)
__device__ __forceinline__ void gbar(unsigned* __restrict__ cnt, unsigned target){
  __syncthreads();
  if(threadIdx.x == 0){
    __threadfence();
    __hip_atomic_fetch_add(&cnt[(blockIdx.x & 63)*16], 1u,
                           __ATOMIC_RELEASE, __HIP_MEMORY_SCOPE_AGENT);
  }
  if(threadIdx.x < 64){
    for(;;){
      unsigned v = __hip_atomic_load(&cnt[threadIdx.x*16],
                                     __ATOMIC_RELAXED, __HIP_MEMORY_SCOPE_AGENT);
      #pragma unroll
      for(int off=32; off; off>>=1) v += __shfl_xor(v, off);
      if(v >= target) break;
      __builtin_amdgcn_s_sleep(2);
    }
  }
  __syncthreads();
  __threadfence();
}

__global__ __launch_bounds__(256, 1)
void k_loop(char* __restrict__ ws, const f32* __restrict__ vvec,
            const int* __restrict__ maskp,
            const f32* __restrict__ b_ih0, const f32* __restrict__ b_hh0,
            const f32* __restrict__ b_ih1, const f32* __restrict__ b_hh1,
            f32* __restrict__ out){
  f32* lin = (f32*)(ws + OFF_LIN);
  const ushort_t* Wdt   = (const ushort_t*)(ws + OFF_WD);
  const ushort_t* Whh0f = (const ushort_t*)(ws + OFF_WHH0);
  const ushort_t* Wih0e = (const ushort_t*)(ws + OFF_WIH0E);
  const ushort_t* Wih0c = (const ushort_t*)(ws + OFF_WIH0C);
  const ushort_t* Wih1f = (const ushort_t*)(ws + OFF_WIH1);
  const ushort_t* Whh1f = (const ushort_t*)(ws + OFF_WHH1);
  f32* g0h = (f32*)(ws + OFF_G0H);      // [4][32][4096]
  f32* g1h = (f32*)(ws + OFF_G1H);      // [4][32][4096]
  f32* g0c = (f32*)(ws + OFF_G0C);      // [4][32][4096]
  f32* g1x = (f32*)(ws + OFF_G1X);      // [4][32][4096]
  f32* hwd = (f32*)(ws + OFF_HWD);      // [4][32][1024]
  const ushort_t* epb  = (const ushort_t*)(ws + OFF_EPB);
  const ushort_t* eob  = (const ushort_t*)(ws + OFF_EOB);
  const ushort_t* embf = (const ushort_t*)(ws + OFF_EMBF);
  f32* c0 = (f32*)(ws + OFF_C0);
  f32* c1 = (f32*)(ws + OFF_C1);
  ushort_t* h0f  = (ushort_t*)(ws + OFF_H0F);
  ushort_t* h1f  = (ushort_t*)(ws + OFF_H1F);
  ushort_t* ctxf = (ushort_t*)(ws + OFF_CTXF);
  unsigned* cnt  = (unsigned*)(ws + OFF_CNT);
  f32* attw = out + OUT_ATT;

  const int tid = threadIdx.x, wid = tid >> 6, lane = tid & 63;
  const int blk = blockIdx.x;
  const int gw = blk*4 + wid;           // 0..1023
  const int ns = gw & 255, kp2 = gw >> 8;

  // 128 KB LDS: per-wave 4 matrices x 8 K-tiles x 1 KB (resident for all 63 steps)
  __shared__ ushort_t wlds[4][4][8][512];
  __shared__ f32 scs[SS];
  __shared__ f32 wsm[SS];

  // ---- stage this block's fixed weight slices into LDS (once) ----
  {
    const ushort_t* srcs[4] = {Whh0f, Whh1f, Wih0c, Wih1f};
    #pragma unroll
    for(int m=0;m<4;m++)
      #pragma unroll
      for(int kti=0;kti<8;kti++){
        int kt = kp2*8 + kti;
        *(u16x8*)&wlds[wid][m][kti][lane*8] =
            *(const u16x8*)(srcs[m] + (((long)ns*32 + kt)<<9) + lane*8);
      }
  }
  __syncthreads();

  f32 vvr[16];
  #pragma unroll
  for(int i=0;i<16;i++) vvr[i] = vvec[lane + 64*i];

  unsigned bar = 0;
  for(int t=0; t<TT; ++t){
    // ---------- Phase A: g0h(+emb), g1h, hWd ----------
    {
      f32x4 a0 = {0.f,0.f,0.f,0.f}, a1 = {0.f,0.f,0.f,0.f};
      gemm_lds8(&wlds[wid][0][0][0], h0f, 32, kp2*8, lane, a0, a1);
      if(kp2 == 0)
        gemm_part(embf + (long)t*16384, 16, Wih0e, 16, ns, 0, 16, lane, a0, a1);
      store_part(g0h + (long)kp2*131072, ns, lane, 4096, a0, a1);
      f32x4 b0 = {0.f,0.f,0.f,0.f}, b1 = {0.f,0.f,0.f,0.f};
      gemm_lds8(&wlds[wid][1][0][0], h1f, 32, kp2*8, lane, b0, b1);
      store_part(g1h + (long)kp2*131072, ns, lane, 4096, b0, b1);
      if(gw >= 768){
        int nsd = gw & 63, kpd = (gw >> 6) & 3;
        f32x4 d0 = {0.f,0.f,0.f,0.f}, d1 = {0.f,0.f,0.f,0.f};
        gemm_part(h1f, 32, Wdt, 32, nsd, kpd*8, 8, lane, d0, d1);
        store_part(hwd + (long)kpd*32768, nsd, lane, 1024, d0, d1);
      }
    }
    bar += 256; gbar(cnt, bar);
    // ---------- Phase B: attention (one block per batch row) ----------
    if(blk < 32){
      int b = blk;
      f32 hwr[16];
      #pragma unroll
      for(int i=0;i<16;i++){
        int off = b*1024 + lane + 64*i;
        hwr[i] = hwd[off] + hwd[32768+off] + hwd[65536+off] + hwd[98304+off];
      }
      #pragma unroll 1
      for(int si=0; si<16; ++si){
        int s = wid*16 + si;
        const ushort_t* ep = epb + ((long)(b*64+s)<<10);
        f32 p = 0.f;
        #pragma unroll
        for(int i=0;i<16;i++){
          f32 e = bf2f(ep[lane + 64*i]);
          p = __builtin_fmaf(vvr[i], fast_tanh(e + hwr[i]), p);
        }
        #pragma unroll
        for(int off=32; off; off>>=1) p += __shfl_down(p, off);
        if(lane == 0) scs[s] = p;
      }
      __syncthreads();
      if(tid < 64){
        int s = tid;
        f32 x = maskp[b*64+s] ? scs[s] : -1e9f;
        f32 m = x;
        #pragma unroll
        for(int off=32; off; off>>=1) m = fmaxf(m, __shfl_xor(m, off));
        f32 e = __expf(x - m);
        f32 sum = e;
        #pragma unroll
        for(int off=32; off; off>>=1) sum += __shfl_xor(sum, off);
        f32 w = e/sum;
        wsm[s] = w;
        attw[(long)t*(BB*SS) + b*64 + s] = w;
      }
      __syncthreads();
      if(tid < 128){
        int d0 = tid*8;
        f32 a[8] = {0.f,0.f,0.f,0.f,0.f,0.f,0.f,0.f};
        const ushort_t* eo = eob + ((long)b<<16) + d0;
        #pragma unroll 8
        for(int s=0;s<64;s++){
          u16x8 v = *(const u16x8*)(eo + ((long)s<<10));
          f32 w = wsm[s];
          #pragma unroll
          for(int j=0;j<8;j++) a[j] = __builtin_fmaf(w, bf2f(v[j]), a[j]);
        }
        f32* ld = lin + (long)(t*BB+b)*LIND + HIDD + d0;
        #pragma unroll
        for(int j=0;j<8;j++) ld[j] = a[j];
        u16x8 cf;
        #pragma unroll
        for(int j=0;j<8;j++) cf[j] = f2bf(a[j]);
        *(u16x8*)(ctxf + frag_idx(b, d0, 32)) = cf;
      }
    }
    bar += 256; gbar(cnt, bar);
    // ---------- Phase C: g0c = ctx @ Wih0c^T ----------
    {
      f32x4 a0 = {0.f,0.f,0.f,0.f}, a1 = {0.f,0.f,0.f,0.f};
      gemm_lds8(&wlds[wid][2][0][0], ctxf, 32, kp2*8, lane, a0, a1);
      store_part(g0c + (long)kp2*131072, ns, lane, 4096, a0, a1);
    }
    bar += 256; gbar(cnt, bar);
    // ---------- Phase D: cell0 ----------
    {
      int g = blk*256 + tid;
      if(g < BB*HIDD){
        int b = g >> 10, j = g & 1023;
        long base = (long)b*4096;
        f32 gv[4];
        #pragma unroll
        for(int q=0;q<4;q++){
          long idx = base + q*1024 + j;
          f32 s = g0h[idx] + g0h[131072+idx] + g0h[262144+idx] + g0h[393216+idx]
                + g0c[idx] + g0c[131072+idx] + g0c[262144+idx] + g0c[393216+idx]
                + b_ih0[q*1024+j] + b_hh0[q*1024+j];
          gv[q] = s;
        }
        f32 cc = fast_sig(gv[1])*c0[g] + fast_sig(gv[0])*fast_tanh(gv[2]);
        f32 hh = fast_sig(gv[3])*fast_tanh(cc);
        c0[g] = cc;
        h0f[frag_idx(b, j, 32)] = f2bf(hh);
      }
    }
    bar += 256; gbar(cnt, bar);
    // ---------- Phase E: g1x = h0_new @ Wih1^T ----------
    {
      f32x4 a0 = {0.f,0.f,0.f,0.f}, a1 = {0.f,0.f,0.f,0.f};
      gemm_lds8(&wlds[wid][3][0][0], h0f, 32, kp2*8, lane, a0, a1);
      store_part(g1x + (long)kp2*131072, ns, lane, 4096, a0, a1);
    }
    bar += 256; gbar(cnt, bar);
    // ---------- Phase F: cell1 ----------
    {
      int g = blk*256 + tid;
      if(g < BB*HIDD){
        int b = g >> 10, j = g & 1023;
        long base = (long)b*4096;
        f32 gv[4];
        #pragma unroll
        for(int q=0;q<4;q++){
          long idx = base + q*1024 + j;
          f32 s = g1h[idx] + g1h[131072+idx] + g1h[262144+idx] + g1h[393216+idx]
                + g1x[idx] + g1x[131072+idx] + g1x[262144+idx] + g1x[393216+idx]
                + b_ih1[q*1024+j] + b_hh1[q*1024+j];
          gv[q] = s;
        }
        f32 cc = fast_sig(gv[1])*c1[g] + fast_sig(gv[0])*fast_tanh(gv[2]);
        f32 hh = fast_sig(gv[3])*fast_tanh(cc);
        c1[g] = cc;
        lin[(long)(t*BB+b)*LIND + j] = hh;
        h1f[frag_idx(b, j, 32)] = f2bf(hh);
      }
    }
    bar += 256; gbar(cnt, bar);
  }
}

// ================= phase-2 MFMA GEMM, B converted inline from f32 =================
template<int NKT, int EPI>
__global__ __launch_bounds__(256)
void k_mfma2(const ushort_t* __restrict__ At, const f32* __restrict__ B,
             int ldb, int nrowsB, int kmaxB,
             const f32* __restrict__ bias, void* __restrict__ Cout){
  const int tid = threadIdx.x, wid = tid >> 6, lane = tid & 63;
  const int wm = wid >> 1, wn = wid & 1;
  const int bm = blockIdx.x, bn = blockIdx.y;
  f32x4 acc[4][4] = {};
  const int rbase = bn*128 + wn*64 + (lane&15);
  const int kb = (lane>>4)*8;
  for(int kt=0; kt<NKT; ++kt){
    bf16x8 af[4], bfr[4];
    #pragma unroll
    for(int i=0;i<4;i++)
      af[i] = *(const bf16x8*)(At + (((long)(bm*8 + wm*4 + i)*NKT + kt)<<9) + lane*8);
    int k0 = kt*32 + kb;
    #pragma unroll
    for(int i=0;i<4;i++){
      int r = rbase + i*16;
      u16x8 v;
      if(r < nrowsB && (k0+8) <= kmaxB){
        float4 x = *(const float4*)(B + (long)r*ldb + k0);
        float4 y = *(const float4*)(B + (long)r*ldb + k0 + 4);
        v[0]=f2bf(x.x); v[1]=f2bf(x.y); v[2]=f2bf(x.z); v[3]=f2bf(x.w);
        v[4]=f2bf(y.x); v[5]=f2bf(y.y); v[6]=f2bf(y.z); v[7]=f2bf(y.w);
      } else {
        #pragma unroll
        for(int j=0;j<8;j++){
          int k = k0+j;
          f32 xx = (r < nrowsB && k < kmaxB) ? B[(long)r*ldb + k] : 0.f;
          v[j] = f2bf(xx);
        }
      }
      bfr[i] = *(bf16x8*)&v;
    }
    #pragma unroll
    for(int mi=0;mi<4;mi++)
      #pragma unroll
      for(int ni=0;ni<4;ni++)
        acc[mi][ni] = __builtin_amdgcn_mfma_f32_16x16x32_bf16(af[mi], bfr[ni], acc[mi][ni], 0, 0, 0);
  }
  #pragma unroll
  for(int mi=0;mi<4;mi++){
    #pragma unroll
    for(int ni=0;ni<4;ni++){
      #pragma unroll
      for(int r=0;r<4;r++){
        int gm = bm*128 + wm*64 + mi*16 + (lane>>4)*4 + r;
        int gn = bn*128 + wn*64 + ni*16 + (lane&15);
        f32 x = acc[mi][ni][r];
        if(EPI == 1){
          x = (gn < INTERD) ? fast_tanh(x + bias[gn]) : 0.f;
          ushort_t* hb = (ushort_t*)Cout;
          int msub = gm >> 4, ktile = gn >> 5;
          int lane_a = (gm & 15) + (((gn & 31) >> 3) << 4);
          hb[(((long)(msub*68 + ktile)) << 9) + lane_a*8 + (gn & 7)] = f2bf(x);
        } else {
          if(gm < TT*BB){
            int tt = gm >> 5, b = gm & 31;
            ((f32*)Cout)[(long)b*TV + (long)tt*VV + gn] = x + bias[gn];
          }
        }
      }
    }
  }
}

extern "C" void kernel_launch(void* const* d_in, const int* in_sizes, int n_in,
                              void* d_out, int out_size, void* d_ws, size_t ws_size,
                              hipStream_t stream){
  (void)in_sizes; (void)n_in; (void)out_size; (void)ws_size;
  const f32* enc_output = (const f32*)d_in[0];
  const int* mask  = (const int*)d_in[1];
  const int* y     = (const int*)d_in[2];
  const f32* dec_h0= (const f32*)d_in[3];
  const f32* dec_c0= (const f32*)d_in[4];
  const f32* emb   = (const f32*)d_in[5];
  const f32* We    = (const f32*)d_in[6];
  const f32* Wd    = (const f32*)d_in[7];
  const f32* vvec  = (const f32*)d_in[8];
  const f32* W_ih0 = (const f32*)d_in[9];
  const f32* W_hh0 = (const f32*)d_in[10];
  const f32* b_ih0 = (const f32*)d_in[11];
  const f32* b_hh0 = (const f32*)d_in[12];
  const f32* W_ih1 = (const f32*)d_in[13];
  const f32* W_hh1 = (const f32*)d_in[14];
  const f32* b_ih1 = (const f32*)d_in[15];
  const f32* b_hh1 = (const f32*)d_in[16];
  const f32* out_W = (const f32*)d_in[17];
  const f32* out_b = (const f32*)d_in[18];
  const f32* sm_W  = (const f32*)d_in[19];
  const f32* sm_b  = (const f32*)d_in[20];
  f32* out = (f32*)d_out;
  char* ws = (char*)d_ws;

  f32* lin       = (f32*)(ws + OFF_LIN);
  f32* enc_proj  = (f32*)(ws + OFF_ENCP);
  ushort_t* epb  = (ushort_t*)(ws + OFF_EPB);
  ushort_t* eob  = (ushort_t*)(ws + OFF_EOB);
  ushort_t* lin_bf = (ushort_t*)(ws + OFF_LINBF);
  ushort_t* hid_bf = (ushort_t*)(ws + OFF_HIDBF);

  // ---- setup ----
  k_setup<<<dim3(256), dim3(256), 0, stream>>>(dec_c0, (f32*)(ws + OFF_C0),
                                               (unsigned*)(ws + OFF_CNT));
  k_fill_emb<<<dim3(4032), dim3(256), 0, stream>>>(emb, y, lin);
  k_gemm_nn<<<dim3(32,16), dim3(256), 0, stream>>>(
      enc_output, We, enc_proj, BB*SS, HIDD, ENCD, ENCD, HIDD, HIDD);
  k_cast<<<dim3(8192), dim3(256), 0, stream>>>(enc_proj, enc_output, epb, eob);

  // ---- weight / state conversions to bf16 fragment tiles ----
  k_conv<<<dim3(512),  dim3(256), 0, stream>>>(Wd,        (ushort_t*)(ws+OFF_WD),   HIDD, HIDD, HIDD, 32, 64L*32, 1);
  k_conv<<<dim3(2048), dim3(256), 0, stream>>>(W_hh0,     (ushort_t*)(ws+OFF_WHH0), HIDD, 4096, HIDD, 32, 256L*32, 0);
  k_conv<<<dim3(1024), dim3(256), 0, stream>>>(W_ih0,     (ushort_t*)(ws+OFF_WIH0E),1536, 4096, 512,  16, 256L*16, 0);
  k_conv<<<dim3(2048), dim3(256), 0, stream>>>(W_ih0+512, (ushort_t*)(ws+OFF_WIH0C),1536, 4096, HIDD, 32, 256L*32, 0);
  k_conv<<<dim3(2048), dim3(256), 0, stream>>>(W_ih1,     (ushort_t*)(ws+OFF_WIH1), HIDD, 4096, HIDD, 32, 256L*32, 0);
  k_conv<<<dim3(2048), dim3(256), 0, stream>>>(W_hh1,     (ushort_t*)(ws+OFF_WHH1), HIDD, 4096, HIDD, 32, 256L*32, 0);
  k_conv<<<dim3(504),  dim3(256), 0, stream>>>(lin+2048,  (ushort_t*)(ws+OFF_EMBF), LIND, TT*BB, 512, 16, 126L*16, 0);
  k_conv<<<dim3(16),   dim3(256), 0, stream>>>(dec_h0,        (ushort_t*)(ws+OFF_H0F), HIDD, BB, HIDD, 32, 64, 0);
  k_conv<<<dim3(16),   dim3(256), 0, stream>>>(dec_h0+32768,  (ushort_t*)(ws+OFF_H1F), HIDD, BB, HIDD, 32, 64, 0);

  // ---- the 63-step recurrence: ONE persistent kernel, LDS-resident weights ----
  k_loop<<<dim3(256), dim3(256), 0, stream>>>(ws, vvec, mask,
      b_ih0, b_hh0, b_ih1, b_hh1, out);

  // ---- phase 2 ----
  k_conv<<<dim3(2560), dim3(256), 0, stream>>>(lin, lin_bf, LIND, TT*BB, LIND, 80, 128L*80, 0);
  k_mfma2<80,1><<<dim3(16,17), dim3(256), 0, stream>>>(
      lin_bf, out_W, LIND, INTERD, LIND, out_b, hid_bf);
  k_mfma2<68,2><<<dim3(16,250), dim3(256), 0, stream>>>(
      hid_bf, sm_W, INTERD, VV, INTERD, sm_b, out);
}

// Round 5
// 7720.802 us; speedup vs baseline: 2.5706x; 2.5706x over previous
//
#include <hip/hip_runtime.h>
#include <hip/hip_bf16.h>

#define BB 32
#define SS 64
#define TT 63
#define EMBD 512
#define ENCD 1024
#define HIDD 1024
#define VV 32000
#define INTERD 2160
#define LIND 2560
#define TV (TT*VV)
#define OUT_ATT ((long)BB*TT*VV)

typedef float f32;
typedef unsigned short ushort_t;
typedef unsigned long long u64;
typedef __attribute__((ext_vector_type(8))) short bf16x8;
typedef __attribute__((ext_vector_type(4))) float f32x4;
typedef __attribute__((ext_vector_type(8))) unsigned short u16x8;

// ---- ws layout (bytes), total ~84.2 MB ----
#define OFF_LIN   0L
#define OFF_WD    20643840L
#define OFF_WHH0  (OFF_WD + 2097152L)
#define OFF_WIH0C (OFF_WHH0 + 8388608L)
#define OFF_WIH1  (OFF_WIH0C + 8388608L)
#define OFF_WHH1  (OFF_WIH1 + 8388608L)
#define OFF_WEND  (OFF_WHH1 + 8388608L)       /* 56,295,424 */
#define OFF_EG    OFF_WEND                     /* embgate bf16 2048x4096 = 16 MB */
#define OFF_ENCP  OFF_WEND                     /* enc_proj f32 8MB, pre-embgate only */
#define OFF_EPB   (OFF_EG + 16777216L)         /* enc_proj bf16 4 MB */
#define OFF_EOB   (OFF_EPB + 4194304L)         /* enc_out  bf16 4 MB */
#define OFF_EMBF  (OFF_EOB + 4194304L)         /* emb frags 2 MB (128 msub x 16 kt) */
#define OFF_HWD   (OFF_EMBF + 2097152L)        /* f32 32x1024 (UC) */
#define OFF_C0    (OFF_HWD + 131072L)
#define OFF_C1    (OFF_C0 + 131072L)
#define OFF_H0F   (OFF_C1 + 131072L)           /* bf16 frags (UC) */
#define OFF_H1F   (OFF_H0F + 65536L)
#define OFF_CTXF  (OFF_H1F + 65536L)
#define OFF_CNT   (OFF_CTXF + 65536L)          /* 8 lines x 64 B */
#define OFF_LINBF OFF_WD                        /* post-loop aliases */
#define OFF_HIDBF (OFF_WD + 10485760L)

__device__ __forceinline__ f32 fast_tanh(f32 x){
    f32 e = __expf(2.0f*x);
    return 1.0f - 2.0f/(e+1.0f);
}
__device__ __forceinline__ f32 fast_sig(f32 x){
    return 1.0f/(1.0f+__expf(-x));
}
__device__ __forceinline__ ushort_t f2bf(f32 x){
    __hip_bfloat16 h = __float2bfloat16(x);
    return *(ushort_t*)&h;
}
__device__ __forceinline__ f32 bf2f(ushort_t u){
    unsigned v = ((unsigned)u) << 16;
    return __uint_as_float(v);
}
// ---- device-scope (UC / LLC-coherent) accessors ----
__device__ __forceinline__ u64 uc_ld8(const u64* p){
  return __hip_atomic_load(p, __ATOMIC_RELAXED, __HIP_MEMORY_SCOPE_AGENT);
}
__device__ __forceinline__ f32 uc_ld4f(const f32* p){
  return __hip_atomic_load(p, __ATOMIC_RELAXED, __HIP_MEMORY_SCOPE_AGENT);
}
__device__ __forceinline__ void uc_st8(u64* p, u64 v){
  __hip_atomic_store(p, v, __ATOMIC_RELAXED, __HIP_MEMORY_SCOPE_AGENT);
}
__device__ __forceinline__ void uc_st4f(f32* p, f32 v){
  __hip_atomic_store(p, v, __ATOMIC_RELAXED, __HIP_MEMORY_SCOPE_AGENT);
}
__device__ __forceinline__ void uc_st2(ushort_t* p, ushort_t v){
  __hip_atomic_store(p, v, __ATOMIC_RELAXED, __HIP_MEMORY_SCOPE_AGENT);
}

// A-fragment element index for (row b<32, k), nkt K-tiles
__device__ __forceinline__ long frag_idx(int b, int k, int nkt){
  return (((long)((b>>4)*nkt + (k>>5)))<<9) + ((b&15) + (((k&31)>>3)<<4))*8 + (k&7);
}

// ================= setup kernels =================
__global__ void k_setup(const f32* __restrict__ c0in, f32* __restrict__ cst,
                        unsigned* __restrict__ cnt){
  int g = blockIdx.x*256 + threadIdx.x;
  if(g < 2*BB*HIDD) cst[g] = c0in[g];     // c0 then c1 contiguous
  if(g < 128) cnt[g] = 0;
}

__global__ void k_fill_emb(const f32* __restrict__ emb_table, const int* __restrict__ y,
                           f32* __restrict__ lin){
  int i = blockIdx.x*256 + threadIdx.x;
  if(i >= TT*BB*EMBD) return;
  int e = i & (EMBD-1);
  int tb = i >> 9; int b = tb & 31; int t = tb >> 5;
  int tok = y[b*64 + t];
  lin[(long)(t*BB+b)*LIND + 2048 + e] = emb_table[(long)tok*EMBD + e];
}

__global__ void k_cast(const f32* __restrict__ ep, const f32* __restrict__ eo,
                       ushort_t* __restrict__ epb, ushort_t* __restrict__ eob){
  int i = blockIdx.x*256 + threadIdx.x;
  if(i >= BB*SS*ENCD) return;
  epb[i] = f2bf(ep[i]);
  eob[i] = f2bf(eo[i]);
}

// ---- fp32 tiled GEMM (enc_proj = enc_output @ We, NN) -- validated r1-r4
__global__ __launch_bounds__(256)
void k_gemm_nn(const f32* __restrict__ A, const f32* __restrict__ Bm,
               f32* __restrict__ C, int M, int N, int K, int lda, int ldb, int ldc){
  __shared__ f32 As[16][72];
  __shared__ f32 Bs[16][72];
  int tid = threadIdx.x;
  int row0 = blockIdx.x*64, col0 = blockIdx.y*64;
  int tx = tid & 15, ty = tid >> 4;
  f32 acc[4][4];
  #pragma unroll
  for(int i=0;i<4;i++)
    #pragma unroll
    for(int j=0;j<4;j++) acc[i][j]=0.f;
  int ra = tid>>2, ka = (tid&3)*4;
  int kb_ = tid>>4, nb = (tid&15)*4;
  for(int k0=0;k0<K;k0+=16){
    {
      float4 a4 = make_float4(0.f,0.f,0.f,0.f);
      int gm = row0 + ra;
      if(gm < M) a4 = *(const float4*)(A + (long)gm*lda + k0 + ka);
      As[ka+0][ra]=a4.x; As[ka+1][ra]=a4.y; As[ka+2][ra]=a4.z; As[ka+3][ra]=a4.w;
    }
    {
      float4 b4 = *(const float4*)(Bm + (long)(k0+kb_)*ldb + col0 + nb);
      *(float4*)&Bs[kb_][nb] = b4;
    }
    __syncthreads();
    #pragma unroll
    for(int kk=0;kk<16;kk++){
      float4 av = *(const float4*)&As[kk][ty*4];
      float4 bv = *(const float4*)&Bs[kk][tx*4];
      const f32* af=(const f32*)&av; const f32* bf=(const f32*)&bv;
      #pragma unroll
      for(int i=0;i<4;i++)
        #pragma unroll
        for(int j=0;j<4;j++) acc[i][j] = __builtin_fmaf(af[i], bf[j], acc[i][j]);
    }
    __syncthreads();
  }
  #pragma unroll
  for(int i=0;i<4;i++){
    int gm = row0 + ty*4 + i;
    if(gm >= M) continue;
    #pragma unroll
    for(int j=0;j<4;j++){
      int gn = col0 + tx*4 + j;
      if(gn >= N) continue;
      C[(long)gm*ldc + gn] = acc[i][j];
    }
  }
}

// ---- fp32 -> bf16 fragment tiles. perm: source row = (r&3)*1024 + (r>>2) (gate interleave).
// tr: source transposed. OOB -> 0.
__global__ void k_conv(const f32* __restrict__ src, ushort_t* __restrict__ dst,
                       int ld, int rows, int kmax, int nkt, long ntiles, int tr, int perm){
  long g = (long)blockIdx.x*256 + threadIdx.x;
  long tile = g >> 6;
  if(tile >= ntiles) return;
  int lane = (int)(g & 63);
  int kt = (int)(tile % nkt);
  int rsub = (int)(tile / nkt);
  int r = rsub*16 + (lane&15);
  int k0 = kt*32 + ((lane>>4)<<3);
  int rs = perm ? ((r&3)*1024 + (r>>2)) : r;
  u16x8 v;
  if(!tr && r < rows && (k0+8) <= kmax){
    float4 a = *(const float4*)(src + (long)rs*ld + k0);
    float4 b = *(const float4*)(src + (long)rs*ld + k0 + 4);
    v[0]=f2bf(a.x); v[1]=f2bf(a.y); v[2]=f2bf(a.z); v[3]=f2bf(a.w);
    v[4]=f2bf(b.x); v[5]=f2bf(b.y); v[6]=f2bf(b.z); v[7]=f2bf(b.w);
  } else {
    #pragma unroll
    for(int j=0;j<8;j++){
      int k = k0+j;
      f32 x = 0.f;
      if(r < rows && k < kmax) x = tr ? src[(long)k*ld + rs] : src[(long)rs*ld + k];
      v[j] = f2bf(x);
    }
  }
  *(u16x8*)(dst + (tile<<9) + lane*8) = v;
}

// ================= persistent loop kernel =================
__device__ __forceinline__ void gemm32(const ushort_t* __restrict__ Ash,
    const ushort_t* __restrict__ Bp, int lane, f32x4& a0, f32x4& a1){
  #pragma unroll 4
  for(int kt=0;kt<32;kt++){
    bf16x8 b  = *(const bf16x8*)(Bp + (kt<<9) + lane*8);
    bf16x8 x0 = *(const bf16x8*)(Ash + (kt<<9) + lane*8);
    bf16x8 x1 = *(const bf16x8*)(Ash + 16384 + (kt<<9) + lane*8);
    a0 = __builtin_amdgcn_mfma_f32_16x16x32_bf16(x0, b, a0, 0, 0, 0);
    a1 = __builtin_amdgcn_mfma_f32_16x16x32_bf16(x1, b, a1, 0, 0, 0);
  }
}

// stage 64KB of UC fragment data into LDS
__device__ __forceinline__ void stageA(ushort_t* Ash, const ushort_t* src, int tid){
  __syncthreads();
  u64* d8 = (u64*)Ash;
  const u64* s8 = (const u64*)src;
  #pragma unroll 8
  for(int c=0;c<32;c++)
    d8[c*256 + tid] = uc_ld8(&s8[c*256 + tid]);
  __syncthreads();
}

// fence-free grid barrier: 8 UC counter lines; release = per-wave vmcnt(0) before add.
__device__ __forceinline__ void gbar(unsigned* __restrict__ cnt, unsigned target,
                                     int tid, int blk){
  asm volatile("s_waitcnt vmcnt(0)" ::: "memory");
  __syncthreads();
  if(tid == 0)
    __hip_atomic_fetch_add(&cnt[(blk & 7)*16], 1u,
                           __ATOMIC_RELAXED, __HIP_MEMORY_SCOPE_AGENT);
  if(tid < 64){
    for(;;){
      unsigned v = (tid < 8) ? __hip_atomic_load(&cnt[tid*16],
                       __ATOMIC_RELAXED, __HIP_MEMORY_SCOPE_AGENT) : 0u;
      v += __shfl_xor(v, 1); v += __shfl_xor(v, 2); v += __shfl_xor(v, 4);
      unsigned tot = __shfl(v, 0);
      if(tot >= target) break;
      __builtin_amdgcn_s_sleep(8);
    }
  }
  __syncthreads();
}

// fused LSTM cell for one batch-half: gate-interleaved acc + shfl butterfly.
__device__ __forceinline__ void cell_half(const f32x4& acc, int bhalf, int lane,
    int ns, int j, f32 bia, const ushort_t* eg_t,
    f32* __restrict__ cst, ushort_t* __restrict__ hdst, f32* __restrict__ lindst){
  int q = (lane&15)&3;
  #pragma unroll
  for(int r=0;r<4;r++){
    int b = bhalf*16 + ((lane>>4)<<2) + r;
    f32 v = acc[r] + bia;
    if(eg_t) v += bf2f(eg_t[(((long)b)<<12) + ns*16 + (lane&15)]);
    f32 x1 = __shfl_xor(v,1), x2 = __shfl_xor(v,2), x3 = __shfl_xor(x1,2);
    f32 gi = q==0? v : q==1? x1 : q==2? x2 : x3;
    f32 gf = q==0? x1: q==1? v  : q==2? x3 : x2;
    f32 gg = q==0? x2: q==1? x3 : q==2? v  : x1;
    f32 go = q==0? x3: q==1? x2 : q==2? x1 : v;
    f32 cold = cst[b*HIDD + j];
    f32 cc = fast_sig(gf)*cold + fast_sig(gi)*fast_tanh(gg);
    f32 hh = fast_sig(go)*fast_tanh(cc);
    if(q == 0){
      cst[b*HIDD + j] = cc;
      uc_st2(hdst + frag_idx(b, j, 32), f2bf(hh));
      if(lindst) lindst[(long)b*LIND + j] = hh;
    }
  }
}

__global__ __launch_bounds__(256, 1)
void k_loop(char* __restrict__ ws, const f32* __restrict__ vvec,
            const int* __restrict__ maskp,
            const f32* __restrict__ b_ih0, const f32* __restrict__ b_hh0,
            const f32* __restrict__ b_ih1, const f32* __restrict__ b_hh1,
            f32* __restrict__ out){
  f32* lin = (f32*)(ws + OFF_LIN);
  const ushort_t* Wdt   = (const ushort_t*)(ws + OFF_WD);
  const ushort_t* Whh0f = (const ushort_t*)(ws + OFF_WHH0);
  const ushort_t* Wih0cf= (const ushort_t*)(ws + OFF_WIH0C);
  const ushort_t* Wih1f = (const ushort_t*)(ws + OFF_WIH1);
  const ushort_t* Whh1f = (const ushort_t*)(ws + OFF_WHH1);
  const ushort_t* eg    = (const ushort_t*)(ws + OFF_EG);
  const ushort_t* epb   = (const ushort_t*)(ws + OFF_EPB);
  const ushort_t* eob   = (const ushort_t*)(ws + OFF_EOB);
  f32* hwd = (f32*)(ws + OFF_HWD);
  f32* c0  = (f32*)(ws + OFF_C0);
  f32* c1  = (f32*)(ws + OFF_C1);
  ushort_t* h0f  = (ushort_t*)(ws + OFF_H0F);
  ushort_t* h1f  = (ushort_t*)(ws + OFF_H1F);
  ushort_t* ctxf = (ushort_t*)(ws + OFF_CTXF);
  unsigned* cnt  = (unsigned*)(ws + OFF_CNT);
  f32* attw = out + OUT_ATT;

  const int tid = threadIdx.x, wid = tid >> 6, lane = tid & 63;
  const int blk = blockIdx.x;
  const int gw = blk*4 + wid;          // 0..255 == ns (gate column slice)
  const int ns = gw;
  const int jj = (lane&15)>>2;
  const int jcol = ns*4 + jj;          // hidden index this quad owns
  const int q0 = (lane&15)&3;
  const int bidx = q0*HIDD + jcol;

  __shared__ ushort_t Ash[32768];      // 64 KB A-fragment staging
  __shared__ f32 scs[SS];
  __shared__ f32 wsm[SS];

  const f32 bia0 = b_ih0[bidx] + b_hh0[bidx];
  const f32 bia1 = b_ih1[bidx] + b_hh1[bidx];
  f32 vvr[16];
  #pragma unroll
  for(int i=0;i<16;i++) vvr[i] = vvec[lane + 64*i];

  // prologue: g0h(0) = h0_init @ Whh0p^T (held in registers)
  stageA(Ash, h0f, tid);
  f32x4 g0a = {0.f,0.f,0.f,0.f}, g0b = {0.f,0.f,0.f,0.f};
  gemm32(Ash, Whh0f + ((long)ns<<14), lane, g0a, g0b);

  unsigned bar = 0;
  for(int t=0; t<TT; ++t){
    // ---------- P1: g1h (regs) + hWd ----------
    stageA(Ash, h1f, tid);
    f32x4 g1a = {0.f,0.f,0.f,0.f}, g1b = {0.f,0.f,0.f,0.f};
    gemm32(Ash, Whh1f + ((long)ns<<14), lane, g1a, g1b);
    if(gw < 64){
      f32x4 da = {0.f,0.f,0.f,0.f}, db = {0.f,0.f,0.f,0.f};
      gemm32(Ash, Wdt + ((long)gw<<14), lane, da, db);
      int col = gw*16 + (lane&15), r0 = (lane>>4)*4;
      #pragma unroll
      for(int r=0;r<4;r++){
        uc_st4f(&hwd[(r0+r)*HIDD + col], da[r]);
        uc_st4f(&hwd[(16+r0+r)*HIDD + col], db[r]);
      }
    }
    bar += 64; gbar(cnt, bar, tid, blk);

    // ---------- P2: attention (blocks 0..31, one per batch row) ----------
    if(blk < BB){
      int b = blk;
      f32 hwr[16];
      #pragma unroll
      for(int i=0;i<16;i++) hwr[i] = uc_ld4f(&hwd[b*HIDD + lane + 64*i]);
      #pragma unroll 1
      for(int si=0; si<16; ++si){
        int s = wid*16 + si;
        const ushort_t* ep = epb + ((long)(b*SS+s)<<10);
        f32 p = 0.f;
        #pragma unroll
        for(int i=0;i<16;i++){
          f32 e = bf2f(ep[lane + 64*i]);
          p = __builtin_fmaf(vvr[i], fast_tanh(e + hwr[i]), p);
        }
        #pragma unroll
        for(int off=32; off; off>>=1) p += __shfl_down(p, off);
        if(lane == 0) scs[s] = p;
      }
      __syncthreads();
      if(tid < 64){
        int s = tid;
        f32 x = maskp[b*SS+s] ? scs[s] : -1e9f;
        f32 m = x;
        #pragma unroll
        for(int off=32; off; off>>=1) m = fmaxf(m, __shfl_xor(m, off));
        f32 e = __expf(x - m);
        f32 sum = e;
        #pragma unroll
        for(int off=32; off; off>>=1) sum += __shfl_xor(sum, off);
        f32 w = e/sum;
        wsm[s] = w;
        attw[(long)t*(BB*SS) + b*SS + s] = w;
      }
      __syncthreads();
      if(tid < 128){
        int d0 = tid*8;
        f32 a[8] = {0.f,0.f,0.f,0.f,0.f,0.f,0.f,0.f};
        const ushort_t* eo = eob + ((long)b<<16) + d0;
        #pragma unroll 8
        for(int s=0;s<SS;s++){
          u16x8 v = *(const u16x8*)(eo + ((long)s<<10));
          f32 w = wsm[s];
          #pragma unroll
          for(int j=0;j<8;j++) a[j] = __builtin_fmaf(w, bf2f(v[j]), a[j]);
        }
        f32* ld = lin + (long)(t*BB+b)*LIND + HIDD + d0;
        #pragma unroll
        for(int j=0;j<8;j++) ld[j] = a[j];
        u64 lo = (u64)f2bf(a[0]) | ((u64)f2bf(a[1])<<16) | ((u64)f2bf(a[2])<<32) | ((u64)f2bf(a[3])<<48);
        u64 hi = (u64)f2bf(a[4]) | ((u64)f2bf(a[5])<<16) | ((u64)f2bf(a[6])<<32) | ((u64)f2bf(a[7])<<48);
        long fi = frag_idx(b, d0, 32);
        uc_st8((u64*)(ctxf + fi), lo);
        uc_st8((u64*)(ctxf + fi + 4), hi);
      }
    }
    bar += 64; gbar(cnt, bar, tid, blk);

    // ---------- P3: g0c accumulate onto g0 regs + fused cell0 ----------
    stageA(Ash, ctxf, tid);
    gemm32(Ash, Wih0cf + ((long)ns<<14), lane, g0a, g0b);
    {
      const ushort_t* eg_t = eg + (((long)(t*BB))<<12);
      cell_half(g0a, 0, lane, ns, jcol, bia0, eg_t, c0, h0f, (f32*)nullptr);
      cell_half(g0b, 1, lane, ns, jcol, bia0, eg_t, c0, h0f, (f32*)nullptr);
    }
    bar += 64; gbar(cnt, bar, tid, blk);

    // ---------- P4: g1x accumulate + fused cell1 + g0h(t+1) ----------
    stageA(Ash, h0f, tid);
    gemm32(Ash, Wih1f + ((long)ns<<14), lane, g1a, g1b);
    {
      f32* lt = lin + (long)t*BB*LIND;
      cell_half(g1a, 0, lane, ns, jcol, bia1, (const ushort_t*)nullptr, c1, h1f, lt);
      cell_half(g1b, 1, lane, ns, jcol, bia1, (const ushort_t*)nullptr, c1, h1f, lt);
    }
    g0a = (f32x4){0.f,0.f,0.f,0.f}; g0b = (f32x4){0.f,0.f,0.f,0.f};
    gemm32(Ash, Whh0f + ((long)ns<<14), lane, g0a, g0b);
    bar += 64; gbar(cnt, bar, tid, blk);
  }
}

// ================= phase-2 MFMA GEMM, B converted inline from f32 =================
// EPI1: tanh(x+bias)->hid_bf frags (nkt 68). EPI2: logits scatter. EPI3: bf16 plain (ldc 4096).
template<int NKT, int EPI, bool PERM>
__global__ __launch_bounds__(256)
void k_mfma2(const ushort_t* __restrict__ At, const f32* __restrict__ B,
             int ldb, int nrowsB, int kmaxB,
             const f32* __restrict__ bias, void* __restrict__ Cout){
  const int tid = threadIdx.x, wid = tid >> 6, lane = tid & 63;
  const int wm = wid >> 1, wn = wid & 1;
  const int bm = blockIdx.x, bn = blockIdx.y;
  f32x4 acc[4][4] = {};
  const int rbase = bn*128 + wn*64 + (lane&15);
  const int kb = (lane>>4)*8;
  for(int kt=0; kt<NKT; ++kt){
    bf16x8 af[4], bfr[4];
    #pragma unroll
    for(int i=0;i<4;i++)
      af[i] = *(const bf16x8*)(At + (((long)(bm*8 + wm*4 + i)*NKT + kt)<<9) + lane*8);
    int k0 = kt*32 + kb;
    #pragma unroll
    for(int i=0;i<4;i++){
      int r = rbase + i*16;
      int rs = PERM ? ((r&3)*1024 + (r>>2)) : r;
      u16x8 v;
      if(r < nrowsB && (k0+8) <= kmaxB){
        float4 x = *(const float4*)(B + (long)rs*ldb + k0);
        float4 y = *(const float4*)(B + (long)rs*ldb + k0 + 4);
        v[0]=f2bf(x.x); v[1]=f2bf(x.y); v[2]=f2bf(x.z); v[3]=f2bf(x.w);
        v[4]=f2bf(y.x); v[5]=f2bf(y.y); v[6]=f2bf(y.z); v[7]=f2bf(y.w);
      } else {
        #pragma unroll
        for(int j=0;j<8;j++){
          int k = k0+j;
          f32 xx = (r < nrowsB && k < kmaxB) ? B[(long)rs*ldb + k] : 0.f;
          v[j] = f2bf(xx);
        }
      }
      bfr[i] = *(bf16x8*)&v;
    }
    #pragma unroll
    for(int mi=0;mi<4;mi++)
      #pragma unroll
      for(int ni=0;ni<4;ni++)
        acc[mi][ni] = __builtin_amdgcn_mfma_f32_16x16x32_bf16(af[mi], bfr[ni], acc[mi][ni], 0, 0, 0);
  }
  #pragma unroll
  for(int mi=0;mi<4;mi++){
    #pragma unroll
    for(int ni=0;ni<4;ni++){
      #pragma unroll
      for(int r=0;r<4;r++){
        int gm = bm*128 + wm*64 + mi*16 + (lane>>4)*4 + r;
        int gn = bn*128 + wn*64 + ni*16 + (lane&15);
        f32 x = acc[mi][ni][r];
        if(EPI == 1){
          x = (gn < INTERD) ? fast_tanh(x + bias[gn]) : 0.f;
          ushort_t* hb = (ushort_t*)Cout;
          int msub = gm >> 4, ktile = gn >> 5;
          int lane_a = (gm & 15) + (((gn & 31) >> 3) << 4);
          hb[(((long)(msub*68 + ktile)) << 9) + lane_a*8 + (gn & 7)] = f2bf(x);
        } else if(EPI == 2){
          if(gm < TT*BB){
            int tt = gm >> 5, b = gm & 31;
            ((f32*)Cout)[(long)b*TV + (long)tt*VV + gn] = x + bias[gn];
          }
        } else {
          ((ushort_t*)Cout)[((long)gm<<12) + gn] = f2bf(x);
        }
      }
    }
  }
}

extern "C" void kernel_launch(void* const* d_in, const int* in_sizes, int n_in,
                              void* d_out, int out_size, void* d_ws, size_t ws_size,
                              hipStream_t stream){
  (void)in_sizes; (void)n_in; (void)out_size; (void)ws_size;
  const f32* enc_output = (const f32*)d_in[0];
  const int* mask  = (const int*)d_in[1];
  const int* y     = (const int*)d_in[2];
  const f32* dec_h0= (const f32*)d_in[3];
  const f32* dec_c0= (const f32*)d_in[4];
  const f32* emb   = (const f32*)d_in[5];
  const f32* We    = (const f32*)d_in[6];
  const f32* Wd    = (const f32*)d_in[7];
  const f32* vvec  = (const f32*)d_in[8];
  const f32* W_ih0 = (const f32*)d_in[9];
  const f32* W_hh0 = (const f32*)d_in[10];
  const f32* b_ih0 = (const f32*)d_in[11];
  const f32* b_hh0 = (const f32*)d_in[12];
  const f32* W_ih1 = (const f32*)d_in[13];
  const f32* W_hh1 = (const f32*)d_in[14];
  const f32* b_ih1 = (const f32*)d_in[15];
  const f32* b_hh1 = (const f32*)d_in[16];
  const f32* out_W = (const f32*)d_in[17];
  const f32* out_b = (const f32*)d_in[18];
  const f32* sm_W  = (const f32*)d_in[19];
  const f32* sm_b  = (const f32*)d_in[20];
  f32* out = (f32*)d_out;
  char* ws = (char*)d_ws;

  f32* lin      = (f32*)(ws + OFF_LIN);
  f32* enc_proj = (f32*)(ws + OFF_ENCP);
  ushort_t* epb = (ushort_t*)(ws + OFF_EPB);
  ushort_t* eob = (ushort_t*)(ws + OFF_EOB);
  ushort_t* embf   = (ushort_t*)(ws + OFF_EMBF);
  ushort_t* egbuf  = (ushort_t*)(ws + OFF_EG);
  ushort_t* lin_bf = (ushort_t*)(ws + OFF_LINBF);
  ushort_t* hid_bf = (ushort_t*)(ws + OFF_HIDBF);

  // ---- setup ----
  k_setup<<<dim3(256), dim3(256), 0, stream>>>(dec_c0, (f32*)(ws + OFF_C0),
                                               (unsigned*)(ws + OFF_CNT));
  k_fill_emb<<<dim3(4032), dim3(256), 0, stream>>>(emb, y, lin);
  k_gemm_nn<<<dim3(32,16), dim3(256), 0, stream>>>(
      enc_output, We, enc_proj, BB*SS, HIDD, ENCD, ENCD, HIDD, HIDD);
  k_cast<<<dim3(8192), dim3(256), 0, stream>>>(enc_proj, enc_output, epb, eob);

  // emb frags (128 msubs x 16 kt, rows 2016 zero-padded)
  k_conv<<<dim3(512),  dim3(256), 0, stream>>>(lin+2048, embf, LIND, TT*BB, 512, 16, 128L*16, 0, 0);
  // embgate = emb @ Wih0e_perm^T -> bf16 [2048][4096]  (overwrites enc_proj region)
  k_mfma2<16,3,true><<<dim3(16,32), dim3(256), 0, stream>>>(
      embf, W_ih0, 1536, 4096, 512, (const f32*)nullptr, egbuf);

  // ---- weight frags (gate-interleaved perm) ----
  k_conv<<<dim3(512),  dim3(256), 0, stream>>>(Wd,        (ushort_t*)(ws+OFF_WD),    HIDD, HIDD, HIDD, 32, 64L*32, 1, 0);
  k_conv<<<dim3(2048), dim3(256), 0, stream>>>(W_hh0,     (ushort_t*)(ws+OFF_WHH0),  HIDD, 4096, HIDD, 32, 256L*32, 0, 1);
  k_conv<<<dim3(2048), dim3(256), 0, stream>>>(W_ih0+512, (ushort_t*)(ws+OFF_WIH0C), 1536, 4096, HIDD, 32, 256L*32, 0, 1);
  k_conv<<<dim3(2048), dim3(256), 0, stream>>>(W_ih1,     (ushort_t*)(ws+OFF_WIH1),  HIDD, 4096, HIDD, 32, 256L*32, 0, 1);
  k_conv<<<dim3(2048), dim3(256), 0, stream>>>(W_hh1,     (ushort_t*)(ws+OFF_WHH1),  HIDD, 4096, HIDD, 32, 256L*32, 0, 1);
  // initial h frags
  k_conv<<<dim3(16),   dim3(256), 0, stream>>>(dec_h0,       (ushort_t*)(ws+OFF_H0F), HIDD, BB, HIDD, 32, 64, 0, 0);
  k_conv<<<dim3(16),   dim3(256), 0, stream>>>(dec_h0+32768, (ushort_t*)(ws+OFF_H1F), HIDD, BB, HIDD, 32, 64, 0, 0);

  // ---- the 63-step recurrence: 64 persistent blocks, fence-free UC protocol ----
  k_loop<<<dim3(64), dim3(256), 0, stream>>>(ws, vvec, mask,
      b_ih0, b_hh0, b_ih1, b_hh1, out);

  // ---- phase 2 ----
  k_conv<<<dim3(2560), dim3(256), 0, stream>>>(lin, lin_bf, LIND, TT*BB, LIND, 80, 128L*80, 0, 0);
  k_mfma2<80,1,false><<<dim3(16,17), dim3(256), 0, stream>>>(
      lin_bf, out_W, LIND, INTERD, LIND, out_b, hid_bf);
  k_mfma2<68,2,false><<<dim3(16,250), dim3(256), 0, stream>>>(
      hid_bf, sm_W, INTERD, VV, INTERD, sm_b, out);
}